// Round 1
// baseline (503.756 us; speedup 1.0000x reference)
//
#include <hip/hip_runtime.h>

#define B_ 16
#define C_ 512
#define S_ 128
#define T_ 2048
#define HALF 18
#define WLEN 37

typedef __bf16 bf16x8 __attribute__((ext_vector_type(8)));
typedef float f32x4 __attribute__((ext_vector_type(4)));
typedef unsigned short ushort8 __attribute__((ext_vector_type(8)));
typedef unsigned short ushort_t;

__device__ inline ushort_t f2bf(float x) {
    unsigned u = __float_as_uint(x);
    u += 0x7fffu + ((u >> 16) & 1u);  // RNE; inputs are finite
    return (ushort_t)(u >> 16);
}
__device__ inline float bf2f(ushort_t h) {
    return __uint_as_float(((unsigned)h) << 16);
}

#define MFMA16(a, b, c) __builtin_amdgcn_mfma_f32_16x16x32_bf16((a), (b), (c), 0, 0, 0)

// ---------------- weight prep: fp32 -> bf16 (+ conv relayout to [o][k*512+i]) ----
__global__ void prep_weights(const float* __restrict__ fc1, const float* __restrict__ fc2,
                             const float* __restrict__ c1, const float* __restrict__ c2,
                             ushort_t* __restrict__ Wfc, ushort_t* __restrict__ Wc1,
                             ushort_t* __restrict__ Wc2) {
    const int n_fc = 1024 * 128;
    const int n_c = 512 * 1536;
    const int total = 2 * n_fc + 2 * n_c;
    for (int idx = blockIdx.x * blockDim.x + threadIdx.x; idx < total;
         idx += gridDim.x * blockDim.x) {
        if (idx < n_fc) {
            Wfc[idx] = f2bf(fc1[idx]);
        } else if (idx < 2 * n_fc) {
            Wfc[idx] = f2bf(fc2[idx - n_fc]);
        } else {
            int r = idx - 2 * n_fc;
            const float* src = c1;
            ushort_t* dst = Wc1;
            if (r >= n_c) { r -= n_c; src = c2; dst = Wc2; }
            int o = r / 1536;
            int rem = r - o * 1536;
            int k = rem >> 9;        // 0..2
            int i = rem & 511;       // in-channel
            dst[o * 1536 + (k << 9) + i] = f2bf(src[(o * 512 + i) * 3 + k]);
        }
    }
}

// ---------------- win_sum(s) over t, output transposed: sw_t[b][t][s] bf16 ------
__global__ __launch_bounds__(256) void winsum_kernel(const float* __restrict__ s,
                                                     ushort_t* __restrict__ sw_t) {
    int b = blockIdx.y;
    int t0 = blockIdx.x * 64;
    __shared__ float sb[128][101];  // stride 101: conflict-free column reads
    int tid = threadIdx.x;
    for (int e = tid; e < 128 * 100; e += 256) {
        int sj = e / 100;
        int u = e - sj * 100;
        int gt = t0 - HALF + u;
        float v = 0.f;
        if (gt >= 0 && gt < T_) v = s[((size_t)(b * S_ + sj)) * T_ + gt];
        sb[sj][u] = v;
    }
    __syncthreads();
    for (int e = tid; e < 64 * 128; e += 256) {
        int tl = e >> 7;
        int sj = e & 127;
        float sum = 0.f;
#pragma unroll
        for (int d = 0; d < WLEN; ++d) sum += sb[sj][tl + d];
        sw_t[((size_t)(b * T_ + t0 + tl)) * S_ + sj] = f2bf(sum);
    }
}

// ---------------- fused adawin instance + leaky-relu ----------------------------
// gamma/beta GEMM (K=128) via MFMA; each wave holds gamma AND beta for the same
// (c,t) elements so the epilogue is lane-local. Output bf16 (conv input).
template <bool IN_BF16>
__global__ __launch_bounds__(256) void adawin_kernel(
    const void* __restrict__ xin_, const ushort_t* __restrict__ sw_t,
    const ushort_t* __restrict__ Wfc, const float* __restrict__ fcb,
    const float* __restrict__ alpha, const int* __restrict__ lengths,
    ushort_t* __restrict__ yout) {
    int t0 = blockIdx.x * 64;
    int c0 = blockIdx.y * 64;
    int b = blockIdx.z;
    __shared__ __attribute__((aligned(16))) ushort_t As[128][136];  // 64 gamma + 64 beta rows, K=128
    __shared__ __attribute__((aligned(16))) ushort_t Bs[64][136];   // [t][k]
    int tid = threadIdx.x;

    {  // stage A: rows 0..63 = Wfc[c0..], rows 64..127 = Wfc[512+c0..]
        int r = tid >> 4;
        int cseg = (tid & 15) * 8;
#pragma unroll
        for (int p = 0; p < 8; ++p) {
            int row = p * 16 + r;
            int grow = (row < 64) ? (c0 + row) : (448 + c0 + row);
            *(uint4*)&As[row][cseg] = *(const uint4*)&Wfc[(size_t)grow * 128 + cseg];
        }
    }
    {  // stage B: sw_t rows are s-contiguous -> vector copies
        int tl = tid & 63;
        int sg = tid >> 6;
        const ushort_t* src = &sw_t[((size_t)(b * T_ + t0 + tl)) * S_];
#pragma unroll
        for (int j = 0; j < 4; ++j) {
            int col = sg * 32 + j * 8;
            *(uint4*)&Bs[tl][col] = *(const uint4*)&src[col];
        }
    }
    __syncthreads();

    int wave = tid >> 6, lane = tid & 63;
    int quad = lane >> 4, l = lane & 15;
    f32x4 accg[4], accb[4];
#pragma unroll
    for (int n = 0; n < 4; ++n) {
        accg[n] = (f32x4){0.f, 0.f, 0.f, 0.f};
        accb[n] = (f32x4){0.f, 0.f, 0.f, 0.f};
    }
    int rg = wave * 16 + l;
    int rb = 64 + wave * 16 + l;
#pragma unroll
    for (int ks = 0; ks < 4; ++ks) {
        int kc = ks * 32 + quad * 8;
        bf16x8 ag = *(const bf16x8*)&As[rg][kc];
        bf16x8 ab = *(const bf16x8*)&As[rb][kc];
#pragma unroll
        for (int n = 0; n < 4; ++n) {
            bf16x8 bb = *(const bf16x8*)&Bs[n * 16 + l][kc];
            accg[n] = MFMA16(ag, bb, accg[n]);
            accb[n] = MFMA16(ab, bb, accb[n]);
        }
    }

    int len = lengths[b];
    float alph = alpha[0];
    const float* xf = (const float*)xin_;
    const ushort_t* xh = (const ushort_t*)xin_;
#pragma unroll
    for (int n = 0; n < 4; ++n) {
        int t = t0 + n * 16 + l;
        int lo = t - HALF; if (lo < 0) lo = 0;
        int hi = t + HALF; if (hi > T_ - 1) hi = T_ - 1;
        float cnt = (float)(hi - lo + 1);
        int hv = hi < (len - 1) ? hi : (len - 1);
        int mdi = hv - lo + 1; if (mdi < 0) mdi = 0;
        float m = (t < len) ? 1.f : 0.f;
        float sc = m / ((float)mdi + 1e-9f);
#pragma unroll
        for (int reg = 0; reg < 4; ++reg) {
            int c = c0 + wave * 16 + quad * 4 + reg;
            size_t off = (size_t)(b * C_ + c) * T_ + t;
            float gamma = (accg[n][reg] + fcb[c] * cnt) * sc;
            float beta = (accb[n][reg] + fcb[C_ + c] * cnt) * sc;
            float xv = IN_BF16 ? bf2f(xh[off]) : xf[off];
            float xn = tanhf(alph * xv);
            float v = (1.f + gamma) * xn + beta;
            v = v > 0.f ? v : 0.2f * v;  // leaky relu (always follows adawin here)
            yout[off] = f2bf(v);
        }
    }
}

// ---------------- conv1d k=3 as implicit MFMA GEMM ------------------------------
// K = 1536 = 3 shifts x 512 in-channels; weights pre-laid-out as [o][k*512+i].
// EPI 0: out = acc + bias -> bf16 (feeds adawin2)
// EPI 1: out = (acc + bias + x) / sqrt(2) -> fp32 (final output)
template <int EPI>
__global__ __launch_bounds__(256) void conv_kernel(
    const ushort_t* __restrict__ Xin, const ushort_t* __restrict__ Wc,
    const float* __restrict__ bias, const float* __restrict__ resid,
    ushort_t* __restrict__ out_bf, float* __restrict__ out_f) {
    int t0 = blockIdx.x * 64;
    int o0 = blockIdx.y * 128;
    int b = blockIdx.z;
    __shared__ __attribute__((aligned(16))) ushort_t As[128][40];
    __shared__ __attribute__((aligned(16))) ushort_t Bs[64][40];
    int tid = threadIdx.x;
    int wave = tid >> 6, lane = tid & 63;
    int quad = lane >> 4, l = lane & 15;

    f32x4 acc[2][4];
#pragma unroll
    for (int s2 = 0; s2 < 2; ++s2)
#pragma unroll
        for (int n = 0; n < 4; ++n) acc[s2][n] = (f32x4){0.f, 0.f, 0.f, 0.f};

    int arow = tid >> 2;
    int aseg = (tid & 3) * 8;
    int tl = tid & 63;
    int ig = tid >> 6;

    for (int ks = 0; ks < 48; ++ks) {
        int kk0 = ks * 32;
        int ksh = kk0 >> 9;       // which of the 3 shifts
        int i0 = kk0 & 511;       // in-channel base
        // stage A (weights): 128 rows x 32 k
        *(uint4*)&As[arow][aseg] =
            *(const uint4*)&Wc[(size_t)(o0 + arow) * 1536 + kk0 + aseg];
        *(uint4*)&As[arow + 64][aseg] =
            *(const uint4*)&Wc[(size_t)(o0 + arow + 64) * 1536 + kk0 + aseg];
        // stage B (shifted input): Bs[t][k], zero at t' outside [0,T)
        int tp = t0 + tl + ksh - 1;
        bool inr = (tp >= 0) && (tp < T_);
        const ushort_t* src = Xin + ((size_t)(b * C_ + i0 + ig * 8)) * T_ + tp;
        ushort8 v;
#pragma unroll
        for (int r = 0; r < 8; ++r) v[r] = inr ? src[(size_t)r * T_] : (ushort_t)0;
        *(ushort8*)&Bs[tl][ig * 8] = v;
        __syncthreads();

        int kc = quad * 8;
        bf16x8 a0 = *(const bf16x8*)&As[wave * 32 + l][kc];
        bf16x8 a1 = *(const bf16x8*)&As[wave * 32 + 16 + l][kc];
#pragma unroll
        for (int n = 0; n < 4; ++n) {
            bf16x8 bb = *(const bf16x8*)&Bs[n * 16 + l][kc];
            acc[0][n] = MFMA16(a0, bb, acc[0][n]);
            acc[1][n] = MFMA16(a1, bb, acc[1][n]);
        }
        __syncthreads();
    }

#pragma unroll
    for (int sub = 0; sub < 2; ++sub)
#pragma unroll
        for (int n = 0; n < 4; ++n) {
            int t = t0 + n * 16 + l;
#pragma unroll
            for (int reg = 0; reg < 4; ++reg) {
                int o = o0 + wave * 32 + sub * 16 + quad * 4 + reg;
                size_t off = (size_t)(b * C_ + o) * T_ + t;
                float v = acc[sub][n][reg] + bias[o];
                if (EPI == 0) {
                    out_bf[off] = f2bf(v);
                } else {
                    out_f[off] = (v + resid[off]) * 0.70710678118654752f;
                }
            }
        }
}

extern "C" void kernel_launch(void* const* d_in, const int* in_sizes, int n_in,
                              void* d_out, int out_size, void* d_ws, size_t ws_size,
                              hipStream_t stream) {
    const float* x = (const float*)d_in[0];
    const float* s = (const float*)d_in[1];
    const int* lengths = (const int*)d_in[2];
    const float* fc1_w = (const float*)d_in[3];
    const float* fc1_b = (const float*)d_in[4];
    const float* alpha1 = (const float*)d_in[5];
    const float* conv1_w = (const float*)d_in[6];
    const float* conv1_b = (const float*)d_in[7];
    const float* fc2_w = (const float*)d_in[8];
    const float* fc2_b = (const float*)d_in[9];
    const float* alpha2 = (const float*)d_in[10];
    const float* conv2_w = (const float*)d_in[11];
    const float* conv2_b = (const float*)d_in[12];

    // workspace carve (all 256B-aligned by construction); total ~75.5 MB
    char* ws = (char*)d_ws;
    ushort_t* sw_t = (ushort_t*)ws; ws += (size_t)B_ * T_ * S_ * 2;       // 8 MB
    ushort_t* Wfc = (ushort_t*)ws;  ws += (size_t)2 * 1024 * 128 * 2;     // 0.5 MB
    ushort_t* Wc1 = (ushort_t*)ws;  ws += (size_t)512 * 1536 * 2;         // 1.5 MB
    ushort_t* Wc2 = (ushort_t*)ws;  ws += (size_t)512 * 1536 * 2;         // 1.5 MB
    ushort_t* y1 = (ushort_t*)ws;   ws += (size_t)B_ * C_ * T_ * 2;       // 32 MB
    ushort_t* y2 = (ushort_t*)ws;   ws += (size_t)B_ * C_ * T_ * 2;       // 32 MB
    if ((size_t)(ws - (char*)d_ws) > ws_size) return;  // fail loudly via validation

    prep_weights<<<dim3(1024), dim3(256), 0, stream>>>(fc1_w, fc2_w, conv1_w, conv2_w,
                                                       Wfc, Wc1, Wc2);
    winsum_kernel<<<dim3(32, 16), dim3(256), 0, stream>>>(s, sw_t);
    adawin_kernel<false><<<dim3(32, 8, 16), dim3(256), 0, stream>>>(
        (const void*)x, sw_t, Wfc, fc1_b, alpha1, lengths, y1);
    conv_kernel<0><<<dim3(32, 4, 16), dim3(256), 0, stream>>>(
        y1, Wc1, conv1_b, (const float*)nullptr, y2, (float*)nullptr);
    adawin_kernel<true><<<dim3(32, 8, 16), dim3(256), 0, stream>>>(
        (const void*)y2, sw_t, Wfc + 1024 * 128, fc2_b, alpha2, lengths, y1);  // y3 aliases y1
    conv_kernel<1><<<dim3(32, 4, 16), dim3(256), 0, stream>>>(
        y1, Wc2, conv2_b, x, (ushort_t*)nullptr, (float*)d_out);
}

// Round 2
// 430.056 us; speedup vs baseline: 1.1714x; 1.1714x over previous
//
#include <hip/hip_runtime.h>

#define B_ 16
#define C_ 512
#define S_ 128
#define T_ 2048
#define HALF 18
#define WLEN 37

typedef __bf16 bf16x8 __attribute__((ext_vector_type(8)));
typedef float f32x4 __attribute__((ext_vector_type(4)));
typedef float f32x16 __attribute__((ext_vector_type(16)));
typedef unsigned short ushort_t;

__device__ inline ushort_t f2bf(float x) {
    unsigned u = __float_as_uint(x);
    u += 0x7fffu + ((u >> 16) & 1u);  // RNE; inputs are finite
    return (ushort_t)(u >> 16);
}
__device__ inline float bf2f(ushort_t h) {
    return __uint_as_float(((unsigned)h) << 16);
}

#define MFMA16(a, b, c) __builtin_amdgcn_mfma_f32_16x16x32_bf16((a), (b), (c), 0, 0, 0)
#define MFMA32(a, b, c) __builtin_amdgcn_mfma_f32_32x32x16_bf16((a), (b), (c), 0, 0, 0)

// ---------------- weight prep: fp32 -> bf16 (+ conv relayout to [o][tap*512+i]) --
__global__ void prep_weights(const float* __restrict__ fc1, const float* __restrict__ fc2,
                             const float* __restrict__ c1, const float* __restrict__ c2,
                             ushort_t* __restrict__ Wfc, ushort_t* __restrict__ Wc1,
                             ushort_t* __restrict__ Wc2) {
    const int n_fc = 1024 * 128;
    const int n_c = 512 * 1536;
    const int total = 2 * n_fc + 2 * n_c;
    for (int idx = blockIdx.x * blockDim.x + threadIdx.x; idx < total;
         idx += gridDim.x * blockDim.x) {
        if (idx < n_fc) {
            Wfc[idx] = f2bf(fc1[idx]);
        } else if (idx < 2 * n_fc) {
            Wfc[idx] = f2bf(fc2[idx - n_fc]);
        } else {
            int r = idx - 2 * n_fc;
            const float* src = c1;
            ushort_t* dst = Wc1;
            if (r >= n_c) { r -= n_c; src = c2; dst = Wc2; }
            int o = r / 1536;
            int rem = r - o * 1536;
            int k = rem >> 9;        // tap 0..2
            int i = rem & 511;       // in-channel
            dst[o * 1536 + (k << 9) + i] = f2bf(src[(o * 512 + i) * 3 + k]);
        }
    }
}

// ---------------- zero the halo rows (t=-1, t=T) of both padded buffers --------
__global__ void zero_pads(ushort_t* __restrict__ y1p, ushort_t* __restrict__ y2p) {
    int tid = blockIdx.x * blockDim.x + threadIdx.x;
    if (tid < 4096) {
        ushort_t* base = (tid & 1) ? y2p : y1p;
        int r = tid >> 1;                 // 0..2047
        int bb = r >> 7;                  // batch
        int rowsel = (r >> 6) & 1;        // 0: t=-1 row, 1: t=T row
        int col = (r & 63) * 8;
        size_t row = (size_t)bb * (T_ + 2) + (rowsel ? (T_ + 1) : 0);
        *(uint4*)&base[row * C_ + col] = (uint4){0, 0, 0, 0};
    }
}

// ---------------- win_sum(s) over t, output transposed: sw_t[b][t][s] bf16 ------
__global__ __launch_bounds__(256) void winsum_kernel(const float* __restrict__ s,
                                                     ushort_t* __restrict__ sw_t) {
    int b = blockIdx.y;
    int t0 = blockIdx.x * 64;
    __shared__ float sb[128][101];
    int tid = threadIdx.x;
    for (int e = tid; e < 128 * 100; e += 256) {
        int sj = e / 100;
        int u = e - sj * 100;
        int gt = t0 - HALF + u;
        float v = 0.f;
        if (gt >= 0 && gt < T_) v = s[((size_t)(b * S_ + sj)) * T_ + gt];
        sb[sj][u] = v;
    }
    __syncthreads();
    for (int e = tid; e < 64 * 128; e += 256) {
        int tl = e >> 7;
        int sj = e & 127;
        float sum = 0.f;
#pragma unroll
        for (int d = 0; d < WLEN; ++d) sum += sb[sj][tl + d];
        sw_t[((size_t)(b * T_ + t0 + tl)) * S_ + sj] = f2bf(sum);
    }
}

// ---------------- fused adawin instance + leaky-relu ----------------------------
// Output: padded [b][T+2][c] bf16 (interior rows only), c-contiguous 8B stores.
// INLAYOUT 0: x is fp32 [b][c][t].  INLAYOUT 1: x is bf16 padded [b][T+2][c].
template <int INLAYOUT>
__global__ __launch_bounds__(256) void adawin_kernel(
    const void* __restrict__ xin_, const ushort_t* __restrict__ sw_t,
    const ushort_t* __restrict__ Wfc, const float* __restrict__ fcb,
    const float* __restrict__ alpha, const int* __restrict__ lengths,
    ushort_t* __restrict__ youtp) {
    int t0 = blockIdx.x * 64;
    int c0 = blockIdx.y * 64;
    int b = blockIdx.z;
    __shared__ __attribute__((aligned(16))) ushort_t As[128][136];
    __shared__ __attribute__((aligned(16))) ushort_t Bs[64][136];
    int tid = threadIdx.x;

    {  // stage A: rows 0..63 = Wfc[c0..] (gamma), 64..127 = Wfc[512+c0..] (beta)
        int r = tid >> 4;
        int cseg = (tid & 15) * 8;
#pragma unroll
        for (int p = 0; p < 8; ++p) {
            int row = p * 16 + r;
            int grow = (row < 64) ? (c0 + row) : (448 + c0 + row);
            *(uint4*)&As[row][cseg] = *(const uint4*)&Wfc[(size_t)grow * 128 + cseg];
        }
    }
    {  // stage B: sw_t rows are s-contiguous
        int tl = tid & 63;
        int sg = tid >> 6;
        const ushort_t* src = &sw_t[((size_t)(b * T_ + t0 + tl)) * S_];
#pragma unroll
        for (int j = 0; j < 4; ++j) {
            int col = sg * 32 + j * 8;
            *(uint4*)&Bs[tl][col] = *(const uint4*)&src[col];
        }
    }
    __syncthreads();

    int wave = tid >> 6, lane = tid & 63;
    int quad = lane >> 4, l = lane & 15;
    f32x4 accg[4], accb[4];
#pragma unroll
    for (int n = 0; n < 4; ++n) {
        accg[n] = (f32x4){0.f, 0.f, 0.f, 0.f};
        accb[n] = (f32x4){0.f, 0.f, 0.f, 0.f};
    }
    int rg = wave * 16 + l;
    int rb = 64 + wave * 16 + l;
#pragma unroll
    for (int ks = 0; ks < 4; ++ks) {
        int kc = ks * 32 + quad * 8;
        bf16x8 ag = *(const bf16x8*)&As[rg][kc];
        bf16x8 ab = *(const bf16x8*)&As[rb][kc];
#pragma unroll
        for (int n = 0; n < 4; ++n) {
            bf16x8 bb = *(const bf16x8*)&Bs[n * 16 + l][kc];
            accg[n] = MFMA16(ag, bb, accg[n]);
            accb[n] = MFMA16(ab, bb, accb[n]);
        }
    }

    int len = lengths[b];
    float alph = alpha[0];
    const float* xf = (const float*)xin_;
    const ushort_t* xh = (const ushort_t*)xin_;
    int cbase = c0 + wave * 16 + quad * 4;
#pragma unroll
    for (int n = 0; n < 4; ++n) {
        int t = t0 + n * 16 + l;
        int lo = t - HALF; if (lo < 0) lo = 0;
        int hi = t + HALF; if (hi > T_ - 1) hi = T_ - 1;
        float cnt = (float)(hi - lo + 1);
        int hv = hi < (len - 1) ? hi : (len - 1);
        int mdi = hv - lo + 1; if (mdi < 0) mdi = 0;
        float m = (t < len) ? 1.f : 0.f;
        float sc = m / ((float)mdi + 1e-9f);

        float xv[4];
        if (INLAYOUT == 0) {
#pragma unroll
            for (int j = 0; j < 4; ++j)
                xv[j] = xf[(size_t)(b * C_ + cbase + j) * T_ + t];
        } else {
            uint2 xraw = *(const uint2*)&xh[((size_t)(b * (T_ + 2) + 1 + t)) * C_ + cbase];
            xv[0] = bf2f((ushort_t)(xraw.x & 0xffff));
            xv[1] = bf2f((ushort_t)(xraw.x >> 16));
            xv[2] = bf2f((ushort_t)(xraw.y & 0xffff));
            xv[3] = bf2f((ushort_t)(xraw.y >> 16));
        }
        unsigned pk[2];
#pragma unroll
        for (int j = 0; j < 4; ++j) {
            int c = cbase + j;
            float gamma = (accg[n][j] + fcb[c] * cnt) * sc;
            float beta = (accb[n][j] + fcb[C_ + c] * cnt) * sc;
            float xn = tanhf(alph * xv[j]);
            float v = (1.f + gamma) * xn + beta;
            v = v > 0.f ? v : 0.2f * v;
            unsigned hv16 = (unsigned)f2bf(v);
            if (j & 1) pk[j >> 1] |= hv16 << 16;
            else pk[j >> 1] = hv16;
        }
        *(uint2*)&youtp[((size_t)(b * (T_ + 2) + 1 + t)) * C_ + cbase] =
            (uint2){pk[0], pk[1]};
    }
}

// ---------------- conv1d k=3 as implicit MFMA GEMM (32x32x16, [t][c] layout) ----
// Block tile: 128 o x 128 t; 4 waves each 64o x 64t (2x2 tiles of 32x32).
// K chunked by 32 in-channels; all 3 taps staged in A; B staged once with halo.
// EPI 0: out = acc + bias -> bf16 padded [b][T+2][c]
// EPI 1: out = (acc + bias + x) / sqrt(2) -> fp32 [b][c][t] (final)
template <int EPI>
__global__ __launch_bounds__(256) void conv_kernel(
    const ushort_t* __restrict__ Xp, const ushort_t* __restrict__ Wc,
    const float* __restrict__ bias, const float* __restrict__ resid,
    ushort_t* __restrict__ out_bf, float* __restrict__ out_f) {
    int t0 = blockIdx.x * 128;
    int o0 = blockIdx.y * 128;
    int b = blockIdx.z;
    __shared__ __attribute__((aligned(16))) ushort_t As[128][104];  // [o][tap*32+k], pad->104
    __shared__ __attribute__((aligned(16))) ushort_t Bs[130][56];   // [t-halo][k], pad->56
    int tid = threadIdx.x;
    int lane = tid & 63, wave = tid >> 6;
    int l32 = lane & 31, khalf = lane >> 5;
    int wo = (wave & 1) * 64, wt = (wave >> 1) * 64;

    f32x16 acc[2][2];
#pragma unroll
    for (int io = 0; io < 2; ++io)
#pragma unroll
        for (int it = 0; it < 2; ++it)
#pragma unroll
            for (int r = 0; r < 16; ++r) acc[io][it][r] = 0.f;

    const ushort_t* xbase = Xp + (size_t)(b * (T_ + 2) + t0) * C_;  // row r <-> t = t0-1+r

#pragma unroll 1
    for (int ch = 0; ch < 16; ++ch) {
        int cb = ch * 32;
        // stage A: 128 rows x 96 cols = 1536 uint4 (6 per thread)
#pragma unroll
        for (int p = 0; p < 6; ++p) {
            int e = p * 256 + tid;
            int row = e / 12, seg = e % 12;
            int tap = seg >> 2, kk = (seg & 3) * 8;
            *(uint4*)&As[row][seg * 8] =
                *(const uint4*)&Wc[(size_t)(o0 + row) * 1536 + tap * 512 + cb + kk];
        }
        // stage B: 130 rows x 32 cols = 520 uint4
#pragma unroll
        for (int p = 0; p < 3; ++p) {
            int e = p * 256 + tid;
            if (e < 520) {
                int r = e >> 2, seg = e & 3;
                *(uint4*)&Bs[r][seg * 8] = *(const uint4*)&xbase[(size_t)r * C_ + cb + seg * 8];
            }
        }
        __syncthreads();
#pragma unroll
        for (int tap = 0; tap < 3; ++tap) {
#pragma unroll
            for (int ks = 0; ks < 2; ++ks) {
                int kc = tap * 32 + ks * 16 + khalf * 8;
                bf16x8 a0 = *(const bf16x8*)&As[wo + l32][kc];
                bf16x8 a1 = *(const bf16x8*)&As[wo + 32 + l32][kc];
#pragma unroll
                for (int it = 0; it < 2; ++it) {
                    bf16x8 bb =
                        *(const bf16x8*)&Bs[wt + it * 32 + l32 + tap][ks * 16 + khalf * 8];
                    acc[0][it] = MFMA32(a0, bb, acc[0][it]);
                    acc[1][it] = MFMA32(a1, bb, acc[1][it]);
                }
            }
        }
        __syncthreads();
    }

    // epilogue: C/D layout col=lane&31 (t), row=(reg&3)+8*(reg>>2)+4*khalf (o)
#pragma unroll
    for (int io = 0; io < 2; ++io)
#pragma unroll
        for (int it = 0; it < 2; ++it) {
            int obase = o0 + wo + io * 64 ? 0 : 0;  // placeholder avoided below
            obase = o0 + wo + io * 32;
            int t = t0 + wt + it * 32 + l32;
            if (EPI == 0) {
                size_t rowoff = ((size_t)(b * (T_ + 2) + 1 + t)) * C_;
#pragma unroll
                for (int g = 0; g < 4; ++g) {
                    int oo = obase + g * 8 + khalf * 4;
                    unsigned pk[2];
#pragma unroll
                    for (int j = 0; j < 4; ++j) {
                        float v = acc[io][it][g * 4 + j] + bias[oo + j];
                        unsigned hv16 = (unsigned)f2bf(v);
                        if (j & 1) pk[j >> 1] |= hv16 << 16;
                        else pk[j >> 1] = hv16;
                    }
                    *(uint2*)&out_bf[rowoff + oo] = (uint2){pk[0], pk[1]};
                }
            } else {
#pragma unroll
                for (int g = 0; g < 4; ++g) {
                    int oo = obase + g * 8 + khalf * 4;
#pragma unroll
                    for (int j = 0; j < 4; ++j) {
                        size_t off = (size_t)(b * C_ + oo + j) * T_ + t;
                        out_f[off] = (acc[io][it][g * 4 + j] + bias[oo + j] + resid[off]) *
                                     0.70710678118654752f;
                    }
                }
            }
        }
}

extern "C" void kernel_launch(void* const* d_in, const int* in_sizes, int n_in,
                              void* d_out, int out_size, void* d_ws, size_t ws_size,
                              hipStream_t stream) {
    const float* x = (const float*)d_in[0];
    const float* s = (const float*)d_in[1];
    const int* lengths = (const int*)d_in[2];
    const float* fc1_w = (const float*)d_in[3];
    const float* fc1_b = (const float*)d_in[4];
    const float* alpha1 = (const float*)d_in[5];
    const float* conv1_w = (const float*)d_in[6];
    const float* conv1_b = (const float*)d_in[7];
    const float* fc2_w = (const float*)d_in[8];
    const float* fc2_b = (const float*)d_in[9];
    const float* alpha2 = (const float*)d_in[10];
    const float* conv2_w = (const float*)d_in[11];
    const float* conv2_b = (const float*)d_in[12];

    char* ws = (char*)d_ws;
    ushort_t* sw_t = (ushort_t*)ws; ws += (size_t)B_ * T_ * S_ * 2;           // 8 MB
    ushort_t* Wfc = (ushort_t*)ws;  ws += (size_t)2 * 1024 * 128 * 2;         // 0.5 MB
    ushort_t* Wc1 = (ushort_t*)ws;  ws += (size_t)512 * 1536 * 2;             // 1.5 MB
    ushort_t* Wc2 = (ushort_t*)ws;  ws += (size_t)512 * 1536 * 2;             // 1.5 MB
    ushort_t* y1p = (ushort_t*)ws;  ws += (size_t)B_ * (T_ + 2) * C_ * 2;     // 33.6 MB
    ushort_t* y2p = (ushort_t*)ws;  ws += (size_t)B_ * (T_ + 2) * C_ * 2;     // 33.6 MB
    if ((size_t)(ws - (char*)d_ws) > ws_size) return;

    prep_weights<<<dim3(1024), dim3(256), 0, stream>>>(fc1_w, fc2_w, conv1_w, conv2_w,
                                                       Wfc, Wc1, Wc2);
    winsum_kernel<<<dim3(32, 16), dim3(256), 0, stream>>>(s, sw_t);
    zero_pads<<<dim3(16), dim3(256), 0, stream>>>(y1p, y2p);
    adawin_kernel<0><<<dim3(32, 8, 16), dim3(256), 0, stream>>>(
        (const void*)x, sw_t, Wfc, fc1_b, alpha1, lengths, y1p);
    conv_kernel<0><<<dim3(16, 4, 16), dim3(256), 0, stream>>>(
        y1p, Wc1, conv1_b, (const float*)nullptr, y2p, (float*)nullptr);
    adawin_kernel<1><<<dim3(32, 8, 16), dim3(256), 0, stream>>>(
        (const void*)y2p, sw_t, Wfc + 1024 * 128, fc2_b, alpha2, lengths, y1p);
    conv_kernel<1><<<dim3(16, 4, 16), dim3(256), 0, stream>>>(
        y1p, Wc2, conv2_b, x, (ushort_t*)nullptr, (float*)d_out);
}